// Round 1
// baseline (154.197 us; speedup 1.0000x reference)
//
#include <hip/hip_runtime.h>

// RankingLoss: B=16384 rows, D=1024 fp32, C=14 int32 labels -> scalar fp32.
// One wave per row; 4 rows/wave; 16 rows/block (256 thr); 1024 blocks.
// Memory-bound: ~134 MB unique read, roofline ~21 us @ 6.3 TB/s.

constexpr int D = 1024;
constexpr int C = 14;
constexpr int ROWS_PER_BLOCK = 16;
constexpr int WAVES_PER_BLOCK = 4;          // 256 threads
constexpr int ROWS_PER_WAVE = ROWS_PER_BLOCK / WAVES_PER_BLOCK;

__global__ __launch_bounds__(256) void ranking_loss_kernel(
    const float* __restrict__ zi, const float* __restrict__ zt,
    const int* __restrict__ labels, float* __restrict__ out, int B)
{
    const int wave = threadIdx.x >> 6;
    const int lane = threadIdx.x & 63;

    float local = 0.0f;  // lane 0 of each wave accumulates its rows' terms

    const int base_row = blockIdx.x * ROWS_PER_BLOCK + wave * ROWS_PER_WAVE;

    for (int k = 0; k < ROWS_PER_WAVE; ++k) {
        const int row = base_row + k;
        int nrow = row + 1;
        if (nrow == B) nrow = 0;

        const float4* zi_r = (const float4*)(zi + (size_t)row  * D);
        const float4* zt_r = (const float4*)(zt + (size_t)row  * D);
        const float4* zi_n = (const float4*)(zi + (size_t)nrow * D);
        const float4* zt_n = (const float4*)(zt + (size_t)nrow * D);

        float paired = 0.0f, imp_img = 0.0f, imp_txt = 0.0f;
        #pragma unroll
        for (int j = 0; j < 4; ++j) {
            const int idx = lane + 64 * j;   // coalesced: lanes contiguous
            const float4 a  = zi_r[idx];     // z_image[row]
            const float4 b  = zt_r[idx];     // z_text[row]
            const float4 an = zi_n[idx];     // z_image[row+1]
            const float4 bn = zt_n[idx];     // z_text[row+1]
            paired  += a.x*b.x  + a.y*b.y  + a.z*b.z  + a.w*b.w;
            imp_img += an.x*b.x + an.y*b.y + an.z*b.z + an.w*b.w;
            imp_txt += bn.x*a.x + bn.y*a.y + bn.z*a.z + bn.w*a.w;
        }

        // Label margin terms: lanes 0..13 each handle one class column.
        // Labels are binary {0,1}: elementwise-equal  <=>  sum(xor)==0.
        float dv = 0.0f, nv = 0.0f;
        if (lane < C) {
            const int li = labels[(size_t)row  * C + lane];
            const int lj = labels[(size_t)nrow * C + lane];
            dv = (float)(li ^ lj);
            nv = (float)(li | lj);
        }

        // Wave-wide reduction of all five partials.
        #pragma unroll
        for (int off = 32; off > 0; off >>= 1) {
            paired  += __shfl_down(paired,  off, 64);
            imp_img += __shfl_down(imp_img, off, 64);
            imp_txt += __shfl_down(imp_txt, off, 64);
            dv      += __shfl_down(dv,      off, 64);
            nv      += __shfl_down(nv,      off, 64);
        }

        if (lane == 0) {
            const float margin =
                (dv == 0.0f) ? 0.0f : fmaxf(0.5f, dv / fmaxf(nv, 1.0f));
            const float t_img = fmaxf(imp_img - paired + margin, 0.0f);
            const float t_txt = fmaxf(imp_txt - paired + margin, 0.0f);
            local += t_img + t_txt;
        }
    }

    __shared__ float smem[WAVES_PER_BLOCK];
    if (lane == 0) smem[wave] = local;
    __syncthreads();
    if (threadIdx.x == 0) {
        float s = 0.0f;
        #pragma unroll
        for (int w = 0; w < WAVES_PER_BLOCK; ++w) s += smem[w];
        atomicAdd(out, s / (float)B);   // 1024 atomics total
    }
}

extern "C" void kernel_launch(void* const* d_in, const int* in_sizes, int n_in,
                              void* d_out, int out_size, void* d_ws, size_t ws_size,
                              hipStream_t stream) {
    const float* zi     = (const float*)d_in[0];
    const float* zt     = (const float*)d_in[1];
    const int*   labels = (const int*)d_in[2];
    float*       out    = (float*)d_out;

    const int B = in_sizes[0] / D;   // 16384

    // Harness poisons d_out with 0xAA before every timed launch.
    hipMemsetAsync(out, 0, (size_t)out_size * sizeof(float), stream);

    const int blocks = B / ROWS_PER_BLOCK;   // 1024
    ranking_loss_kernel<<<blocks, 256, 0, stream>>>(zi, zt, labels, out, B);
}

// Round 2
// 150.032 us; speedup vs baseline: 1.0278x; 1.0278x over previous
//
#include <hip/hip_runtime.h>

// RankingLoss: B=16384 rows, D=1024 fp32, C=14 int32 labels -> scalar fp32.
//
// Phase 1: wave handles 4 consecutive OUTPUT rows r..r+3, loading data rows
// r..r+4 (imposter sharing: row k+1 is both "imposter of k" and "paired of
// k+1") -> 10 float4 loads per K-quarter, all issued before use (high MLP).
// Label margins via 2 ballots (no shuffle chain). 12 dot partials reduced by
// wave shuffles once per 4 rows. Per-block partial -> d_ws (no atomics).
// Phase 2: one block reduces 1024 partials deterministically -> d_out.

constexpr int D   = 1024;
constexpr int C   = 14;
constexpr int RPW = 4;          // output rows per wave
constexpr int WPB = 4;          // waves per block (256 threads)
constexpr int RPB = RPW * WPB;  // 16 output rows per block

__device__ __forceinline__ float dot4(const float4 x, const float4 y) {
    return x.x * y.x + x.y * y.y + x.z * y.z + x.w * y.w;
}

__global__ __launch_bounds__(256) void rank_phase1(
    const float* __restrict__ zi, const float* __restrict__ zt,
    const int* __restrict__ labels, float* __restrict__ partial, int B)
{
    const int wave = threadIdx.x >> 6;
    const int lane = threadIdx.x & 63;
    const int r0   = blockIdx.x * RPB + wave * RPW;
    const int M    = B - 1;  // B is a power of two

    // Wave-uniform row base pointers for rows r0..r0+4 (wrap at B).
    const float4* zi_r[RPW + 1];
    const float4* zt_r[RPW + 1];
    #pragma unroll
    for (int k = 0; k <= RPW; ++k) {
        const int r = (r0 + k) & M;
        zi_r[k] = (const float4*)(zi + (size_t)r * D);
        zt_r[k] = (const float4*)(zt + (size_t)r * D);
    }

    float p [RPW] = {0.f, 0.f, 0.f, 0.f};  // paired   dot(zi[k],  zt[k])
    float ii[RPW] = {0.f, 0.f, 0.f, 0.f};  // imp_img  dot(zi[k+1],zt[k])
    float it[RPW] = {0.f, 0.f, 0.f, 0.f};  // imp_txt  dot(zt[k+1],zi[k])

    #pragma unroll
    for (int j = 0; j < 4; ++j) {
        const int idx = lane + 64 * j;  // lanes contiguous -> 1 KiB/instr
        // Batch ALL 10 loads for this quarter before any FMA.
        float4 a[RPW + 1], b[RPW + 1];
        #pragma unroll
        for (int k = 0; k <= RPW; ++k) a[k] = zi_r[k][idx];
        #pragma unroll
        for (int k = 0; k <= RPW; ++k) b[k] = zt_r[k][idx];
        #pragma unroll
        for (int k = 0; k < RPW; ++k) {
            p [k] += dot4(a[k],     b[k]);
            ii[k] += dot4(a[k + 1], b[k]);
            it[k] += dot4(b[k + 1], a[k]);
        }
    }

    // Label margins via ballot: lane = 16*k + c covers class c of row r0+k.
    // Binary labels: dv = popcount(xor bits), nv = popcount(or bits).
    const int kk = lane >> 4;
    const int c  = lane & 15;
    int lx = 0, lo = 0;
    if (c < C) {
        const int ra = (r0 + kk)     & M;
        const int rb = (r0 + kk + 1) & M;
        const int li = labels[(size_t)ra * C + c];
        const int lj = labels[(size_t)rb * C + c];
        lx = li ^ lj;
        lo = li | lj;
    }
    const unsigned long long bx = __ballot(lx != 0);
    const unsigned long long bo = __ballot(lo != 0);

    // Wave-reduce the 12 dot partials (independent chains pipeline well).
    #pragma unroll
    for (int off = 32; off > 0; off >>= 1) {
        #pragma unroll
        for (int k = 0; k < RPW; ++k) {
            p [k] += __shfl_down(p [k], off, 64);
            ii[k] += __shfl_down(ii[k], off, 64);
            it[k] += __shfl_down(it[k], off, 64);
        }
    }

    float local = 0.f;
    if (lane == 0) {
        #pragma unroll
        for (int k = 0; k < RPW; ++k) {
            const float dv = (float)__popcll((bx >> (16 * k)) & 0x3FFFull);
            const float nv = (float)__popcll((bo >> (16 * k)) & 0x3FFFull);
            const float m  = (dv == 0.f) ? 0.f : fmaxf(0.5f, dv / nv);
            local += fmaxf(ii[k] - p[k] + m, 0.f)
                   + fmaxf(it[k] - p[k] + m, 0.f);
        }
    }

    __shared__ float smem[WPB];
    if (lane == 0) smem[wave] = local;
    __syncthreads();
    if (threadIdx.x == 0)
        partial[blockIdx.x] = smem[0] + smem[1] + smem[2] + smem[3];
}

__global__ __launch_bounds__(256) void rank_phase2(
    const float* __restrict__ partial, float* __restrict__ out,
    int npart, float invB)
{
    float s = 0.f;
    for (int i = threadIdx.x; i < npart; i += 256) s += partial[i];
    #pragma unroll
    for (int off = 32; off > 0; off >>= 1) s += __shfl_down(s, off, 64);
    __shared__ float sm[4];
    if ((threadIdx.x & 63) == 0) sm[threadIdx.x >> 6] = s;
    __syncthreads();
    if (threadIdx.x == 0)
        out[0] = (sm[0] + sm[1] + sm[2] + sm[3]) * invB;
}

extern "C" void kernel_launch(void* const* d_in, const int* in_sizes, int n_in,
                              void* d_out, int out_size, void* d_ws, size_t ws_size,
                              hipStream_t stream) {
    const float* zi     = (const float*)d_in[0];
    const float* zt     = (const float*)d_in[1];
    const int*   labels = (const int*)d_in[2];
    float*       out    = (float*)d_out;
    float*       ws     = (float*)d_ws;

    const int B      = in_sizes[0] / D;  // 16384
    const int blocks = B / RPB;          // 1024

    rank_phase1<<<blocks, 256, 0, stream>>>(zi, zt, labels, ws, B);
    rank_phase2<<<1, 256, 0, stream>>>(ws, out, blocks, 1.0f / (float)B);
}